// Round 1
// baseline (232.247 us; speedup 1.0000x reference)
//
#include <hip/hip_runtime.h>
#include <hip/hip_bf16.h>
#include <stdint.h>

// ---------------------------------------------------------------------------
// BinaryLinear: out[M,N] = x[M,K] @ sign(W[N,K])^T + bias[N]
// M=8192, K=2048, N=2048, fp32 in/out.
// Strategy: convert x -> bf16 (RNE), W -> sign in bf16 (+-1.0), then
// m97-style bf16 MFMA GEMM (128x128 tile, BK=32, global_load_lds width=16),
// fp32 accumulate, fused bias epilogue.
// ---------------------------------------------------------------------------

typedef __bf16 bf16x8 __attribute__((ext_vector_type(8)));
typedef float f32x4 __attribute__((ext_vector_type(4)));

typedef const __attribute__((address_space(1))) void* gas_ptr;
typedef __attribute__((address_space(3))) void* lds_ptr;

__device__ __forceinline__ unsigned short f2bf_rne(float f) {
    unsigned int u = __builtin_bit_cast(unsigned int, f);
    u += 0x7fffu + ((u >> 16) & 1u);   // round-to-nearest-even
    return (unsigned short)(u >> 16);
}

// x fp32 -> bf16 bits, 8 elements/thread (two float4 loads, one uint4 store)
__global__ __launch_bounds__(256) void cvt_x_kernel(const float* __restrict__ in,
                                                    unsigned short* __restrict__ out,
                                                    int n8) {
    int i = blockIdx.x * 256 + threadIdx.x;
    if (i >= n8) return;
    const float4* p = reinterpret_cast<const float4*>(in + (size_t)i * 8);
    float4 f0 = p[0], f1 = p[1];
    union { unsigned short s[8]; uint4 v; } o;
    o.s[0] = f2bf_rne(f0.x); o.s[1] = f2bf_rne(f0.y);
    o.s[2] = f2bf_rne(f0.z); o.s[3] = f2bf_rne(f0.w);
    o.s[4] = f2bf_rne(f1.x); o.s[5] = f2bf_rne(f1.y);
    o.s[6] = f2bf_rne(f1.z); o.s[7] = f2bf_rne(f1.w);
    *reinterpret_cast<uint4*>(out + (size_t)i * 8) = o.v;
}

// W fp32 -> sign(W) as bf16 bits (+1.0 / -1.0); w>=0 -> +1 per reference
__global__ __launch_bounds__(256) void bin_w_kernel(const float* __restrict__ in,
                                                    unsigned short* __restrict__ out,
                                                    int n8) {
    int i = blockIdx.x * 256 + threadIdx.x;
    if (i >= n8) return;
    const float4* p = reinterpret_cast<const float4*>(in + (size_t)i * 8);
    float4 f0 = p[0], f1 = p[1];
    union { unsigned short s[8]; uint4 v; } o;
    o.s[0] = (f0.x >= 0.f) ? 0x3F80u : 0xBF80u;
    o.s[1] = (f0.y >= 0.f) ? 0x3F80u : 0xBF80u;
    o.s[2] = (f0.z >= 0.f) ? 0x3F80u : 0xBF80u;
    o.s[3] = (f0.w >= 0.f) ? 0x3F80u : 0xBF80u;
    o.s[4] = (f1.x >= 0.f) ? 0x3F80u : 0xBF80u;
    o.s[5] = (f1.y >= 0.f) ? 0x3F80u : 0xBF80u;
    o.s[6] = (f1.z >= 0.f) ? 0x3F80u : 0xBF80u;
    o.s[7] = (f1.w >= 0.f) ? 0x3F80u : 0xBF80u;
    *reinterpret_cast<uint4*>(out + (size_t)i * 8) = o.v;
}

// ---------------------------------------------------------------------------
// GEMM: C[M,N] = A[M,K] (bf16) * B[N,K]^T (bf16) + bias[N], fp32 out.
// 128x128 block tile, BK=32, 256 threads = 4 waves as 2x2, each wave does a
// 64x64 subtile via 4x4 grid of mfma_f32_16x16x32_bf16.
// LDS: A-tile 128x32 bf16 row-major (8 KB) + B-tile same (8 KB), unpadded
// (global_load_lds requires contiguous lane order: base + lane*16).
// ---------------------------------------------------------------------------
#define TILE 128
#define BK   32

__global__ __launch_bounds__(256) void gemm_bin_kernel(
    const unsigned short* __restrict__ A,   // bf16 bits [M][K]
    const unsigned short* __restrict__ B,   // bf16 bits [N][K]
    const float* __restrict__ bias,         // [N]
    float* __restrict__ C,                  // [M][N]
    int M, int N, int K)
{
    __shared__ unsigned short Als[TILE * BK];  // 8 KB
    __shared__ unsigned short Bls[TILE * BK];  // 8 KB

    const int tid  = threadIdx.x;
    const int lane = tid & 63;
    const int wave = tid >> 6;
    const int wm   = wave & 1;    // wave row within 2x2
    const int wn   = wave >> 1;   // wave col within 2x2

    const int bm = blockIdx.y;    // M/128 = 64
    const int bn = blockIdx.x;    // N/128 = 16

    const unsigned short* Ag = A + (size_t)bm * TILE * K;
    const unsigned short* Bg = B + (size_t)bn * TILE * K;

    // Staging: tile = 128 rows x 32 cols = 4096 bf16 = 8 KB.
    // Chunk g (8 bf16 = 16 B): row = g>>2, col = (g&3)*8. Thread t stages
    // chunks t and 256+t. LDS dest offset = g*16 B = (uniform base) + lane*16.
    const int g0 = tid;
    const int g1 = 256 + tid;
    const int r0 = g0 >> 2, c0 = (g0 & 3) * 8;
    const int r1 = g1 >> 2, c1 = (g1 & 3) * 8;

    f32x4 acc[4][4];
#pragma unroll
    for (int a = 0; a < 4; ++a)
#pragma unroll
        for (int b = 0; b < 4; ++b)
            acc[a][b] = {0.f, 0.f, 0.f, 0.f};

    const int laneM = lane & 15;       // row (A) / col (B,n) within 16-tile
    const int laneQ = lane >> 4;       // k-quad
    const int ldsKOff = laneQ * 8;

    for (int k0 = 0; k0 < K; k0 += BK) {
        __builtin_amdgcn_global_load_lds(
            (gas_ptr)(Ag + (size_t)r0 * K + k0 + c0),
            (lds_ptr)(&Als[g0 * 8]), 16, 0, 0);
        __builtin_amdgcn_global_load_lds(
            (gas_ptr)(Ag + (size_t)r1 * K + k0 + c1),
            (lds_ptr)(&Als[g1 * 8]), 16, 0, 0);
        __builtin_amdgcn_global_load_lds(
            (gas_ptr)(Bg + (size_t)r0 * K + k0 + c0),
            (lds_ptr)(&Bls[g0 * 8]), 16, 0, 0);
        __builtin_amdgcn_global_load_lds(
            (gas_ptr)(Bg + (size_t)r1 * K + k0 + c1),
            (lds_ptr)(&Bls[g1 * 8]), 16, 0, 0);

        __syncthreads();

        bf16x8 af[4], bfr[4];
#pragma unroll
        for (int mi = 0; mi < 4; ++mi) {
            int row = wm * 64 + mi * 16 + laneM;
            af[mi] = *reinterpret_cast<const bf16x8*>(&Als[row * BK + ldsKOff]);
        }
#pragma unroll
        for (int ni = 0; ni < 4; ++ni) {
            int row = wn * 64 + ni * 16 + laneM;
            bfr[ni] = *reinterpret_cast<const bf16x8*>(&Bls[row * BK + ldsKOff]);
        }

#pragma unroll
        for (int mi = 0; mi < 4; ++mi)
#pragma unroll
            for (int ni = 0; ni < 4; ++ni)
                acc[mi][ni] = __builtin_amdgcn_mfma_f32_16x16x32_bf16(
                    af[mi], bfr[ni], acc[mi][ni], 0, 0, 0);

        __syncthreads();
    }

    // Epilogue. C/D layout: col = lane&15, row = (lane>>4)*4 + reg.
    const int colBase = bn * TILE + wn * 64 + laneM;
    const int rowBase = bm * TILE + wm * 64 + laneQ * 4;
#pragma unroll
    for (int ni = 0; ni < 4; ++ni) {
        int col = colBase + ni * 16;
        float bv = bias[col];
#pragma unroll
        for (int mi = 0; mi < 4; ++mi) {
            int row = rowBase + mi * 16;
#pragma unroll
            for (int r = 0; r < 4; ++r) {
                C[(size_t)(row + r) * N + col] = acc[mi][ni][r] + bv;
            }
        }
    }
}

extern "C" void kernel_launch(void* const* d_in, const int* in_sizes, int n_in,
                              void* d_out, int out_size, void* d_ws, size_t ws_size,
                              hipStream_t stream) {
    const float* x    = (const float*)d_in[0];   // [M, K]
    const float* w    = (const float*)d_in[1];   // [N, K]
    const float* bias = (const float*)d_in[2];   // [N]
    float* out = (float*)d_out;

    const int K = 2048;                 // IN
    const int N = in_sizes[2];          // OUT = 2048
    const int M = in_sizes[0] / K;      // 8192

    unsigned short* xb = (unsigned short*)d_ws;            // [M,K] bf16: 32 MB
    unsigned short* wb = xb + (size_t)M * K;               // [N,K] bf16:  8 MB

    const int nx8 = (M * K) / 8;
    const int nw8 = (N * K) / 8;
    cvt_x_kernel<<<(nx8 + 255) / 256, 256, 0, stream>>>(x, xb, nx8);
    bin_w_kernel<<<(nw8 + 255) / 256, 256, 0, stream>>>(w, wb, nw8);

    dim3 grid(N / TILE, M / TILE);      // (16, 64)
    gemm_bin_kernel<<<grid, 256, 0, stream>>>(xb, wb, bias, out, M, N, K);
}

// Round 3
// 223.586 us; speedup vs baseline: 1.0387x; 1.0387x over previous
//
#include <hip/hip_runtime.h>
#include <stdint.h>

// ---------------------------------------------------------------------------
// BinaryLinear: out[M,N] = x[M,K] @ sign(W[N,K])^T + bias[N]
// M=8192, K=2048, N=2048, fp32 in/out.
// Round 3: round-2 design (fused x->bf16 conversion inside the GEMM,
// B from bin_w prep via global_load_lds) with the epilogue LDS transpose
// FIXED: __syncthreads() fences between write and read phases (round 2's
// unfenced wave-synchronous transpose allowed the compiler to reorder the
// float4 ds_reads above the float ds_writes -> absmax 304).
// ---------------------------------------------------------------------------

typedef __bf16 bf16x8 __attribute__((ext_vector_type(8)));
typedef float f32x4 __attribute__((ext_vector_type(4)));

typedef const __attribute__((address_space(1))) void* gas_ptr;
typedef __attribute__((address_space(3))) void* lds_ptr;

__device__ __forceinline__ unsigned short f2bf_rne(float f) {
    unsigned int u = __builtin_bit_cast(unsigned int, f);
    u += 0x7fffu + ((u >> 16) & 1u);   // round-to-nearest-even
    return (unsigned short)(u >> 16);
}

__device__ __forceinline__ uint4 pack8(float4 a, float4 b) {
    union { unsigned short s[8]; uint4 v; } o;
    o.s[0] = f2bf_rne(a.x); o.s[1] = f2bf_rne(a.y);
    o.s[2] = f2bf_rne(a.z); o.s[3] = f2bf_rne(a.w);
    o.s[4] = f2bf_rne(b.x); o.s[5] = f2bf_rne(b.y);
    o.s[6] = f2bf_rne(b.z); o.s[7] = f2bf_rne(b.w);
    return o.v;
}

// W fp32 -> sign(W) as bf16 bits (+1.0/-1.0). w>=0 -> +1 per reference.
__global__ __launch_bounds__(256) void bin_w_kernel(const float* __restrict__ in,
                                                    unsigned short* __restrict__ out,
                                                    int n4) {
    int i = blockIdx.x * 256 + threadIdx.x;
    if (i >= n4) return;
    float4 f = reinterpret_cast<const float4*>(in)[i];
    union { unsigned short s[4]; uint2 v; } o;
    o.s[0] = (f.x >= 0.f) ? 0x3F80u : 0xBF80u;
    o.s[1] = (f.y >= 0.f) ? 0x3F80u : 0xBF80u;
    o.s[2] = (f.z >= 0.f) ? 0x3F80u : 0xBF80u;
    o.s[3] = (f.w >= 0.f) ? 0x3F80u : 0xBF80u;
    reinterpret_cast<uint2*>(out)[i] = o.v;
}

// ---------------------------------------------------------------------------
// Fused GEMM: C[M,N] = cvt_bf16(X[M,K]) * Bw[N,K]^T + bias, fp32 accumulate.
// 128x128 tile, BK=32, 4 waves (2x2), 4x4 mfma_f32_16x16x32_bf16 per wave.
// A: fp32 global -> regs (prefetched one BK ahead) -> cvt -> ds_write_b128.
// B: global_load_lds width=16 (bf16 +-1 from bin_w prep in d_ws).
// Epilogue: LDS transpose (wave-private 4KB regions, barrier-fenced) ->
// global_store_dwordx4, 4 x 256B contiguous segments per instruction.
// ---------------------------------------------------------------------------
#define TILE 128
#define BK   32

__global__ __launch_bounds__(256) void gemm_fused_kernel(
    const float* __restrict__ X,            // [M][K] fp32
    const unsigned short* __restrict__ Bw,  // [N][K] bf16 bits (+-1)
    const float* __restrict__ bias,         // [N]
    float* __restrict__ C,                  // [M][N]
    int M, int N, int K)
{
    __shared__ __align__(16) unsigned char smem[16384];
    unsigned short* Als = (unsigned short*)smem;           // [128][32] bf16
    unsigned short* Bls = (unsigned short*)(smem + 8192);  // [128][32] bf16

    const int tid  = threadIdx.x;
    const int lane = tid & 63;
    const int wave = tid >> 6;
    const int wm   = wave & 1;
    const int wn   = wave >> 1;
    const int bm   = blockIdx.y;   // M/128 = 64
    const int bn   = blockIdx.x;   // N/128 = 16

    // Staging assignment: tile = 128 rows x 32 cols; chunk = 8 elems.
    // Thread t owns (row r0, cols kc..kc+7) and (row r0+64, same cols).
    // LDS byte offset = tid*16 -> per-wave uniform base + lane*16 (gld_lds ok).
    const int r0 = tid >> 2;             // 0..63
    const int r1 = r0 + 64;
    const int kc = (tid & 3) * 8;

    const float*          Ag0 = X  + (size_t)(bm * TILE + r0) * K + kc;
    const float*          Ag1 = Ag0 + (size_t)64 * K;
    const unsigned short* Bg0 = Bw + (size_t)(bn * TILE + r0) * K + kc;
    const unsigned short* Bg1 = Bg0 + (size_t)64 * K;

    f32x4 acc[4][4];
#pragma unroll
    for (int a = 0; a < 4; ++a)
#pragma unroll
        for (int b = 0; b < 4; ++b)
            acc[a][b] = {0.f, 0.f, 0.f, 0.f};

    const int laneM = lane & 15;
    const int laneQ = lane >> 4;
    const int koff  = laneQ * 8;

    // Prefetch A for k0 = 0 (fp32, 8 floats per owned row-chunk).
    float4 pa0 = *(const float4*)(Ag0);
    float4 pa1 = *(const float4*)(Ag0 + 4);
    float4 pb0 = *(const float4*)(Ag1);
    float4 pb1 = *(const float4*)(Ag1 + 4);

    for (int k0 = 0; k0 < K; k0 += BK) {
        __syncthreads();   // previous iteration's frag reads complete

        // B tile: async global->LDS (bf16 already)
        __builtin_amdgcn_global_load_lds((gas_ptr)(Bg0 + k0),
                                         (lds_ptr)&Bls[r0 * BK + kc], 16, 0, 0);
        __builtin_amdgcn_global_load_lds((gas_ptr)(Bg1 + k0),
                                         (lds_ptr)&Bls[r1 * BK + kc], 16, 0, 0);

        // A tile: convert prefetched fp32 regs -> bf16, stage to LDS
        *reinterpret_cast<uint4*>(&Als[r0 * BK + kc]) = pack8(pa0, pa1);
        *reinterpret_cast<uint4*>(&Als[r1 * BK + kc]) = pack8(pb0, pb1);

        // Prefetch A for next iteration (latency hides under B's vmcnt wait)
        if (k0 + BK < K) {
            pa0 = *(const float4*)(Ag0 + k0 + BK);
            pa1 = *(const float4*)(Ag0 + k0 + BK + 4);
            pb0 = *(const float4*)(Ag1 + k0 + BK);
            pb1 = *(const float4*)(Ag1 + k0 + BK + 4);
        }

        __syncthreads();   // staging complete (vmcnt + lgkmcnt drained)

        bf16x8 af[4], bfr[4];
#pragma unroll
        for (int mi = 0; mi < 4; ++mi) {
            int row = wm * 64 + mi * 16 + laneM;
            af[mi] = *reinterpret_cast<const bf16x8*>(&Als[row * BK + koff]);
        }
#pragma unroll
        for (int ni = 0; ni < 4; ++ni) {
            int row = wn * 64 + ni * 16 + laneM;
            bfr[ni] = *reinterpret_cast<const bf16x8*>(&Bls[row * BK + koff]);
        }

#pragma unroll
        for (int mi = 0; mi < 4; ++mi)
#pragma unroll
            for (int ni = 0; ni < 4; ++ni)
                acc[mi][ni] = __builtin_amdgcn_mfma_f32_16x16x32_bf16(
                    af[mi], bfr[ni], acc[mi][ni], 0, 0, 0);
    }

    // Epilogue: per-wave private 16x64 fp32 staging area (4 KB), transpose
    // from MFMA C/D layout (col=lane&15, row=quad*4+reg) to row-contiguous,
    // then float4 stores: 4 rows x 256 B contiguous per instruction.
    // All waves execute this loop uniformly -> in-loop barriers are legal.
    // Barriers fence the cross-lane LDS dependency (round-2 bug: without
    // them the compiler may hoist the float4 reads above the writes).
    float* eps = (float*)smem + wave * 1024;  // 16*64 floats per wave
    const int ec = laneM * 4;                  // read-phase col (floats)
    float4 bv = *(const float4*)&bias[bn * TILE + wn * 64 + ec];

#pragma unroll
    for (int mi = 0; mi < 4; ++mi) {
        __syncthreads();   // eps free: prior frag reads / prior mi reads done
#pragma unroll
        for (int ni = 0; ni < 4; ++ni)
#pragma unroll
            for (int r = 0; r < 4; ++r)
                eps[(laneQ * 4 + r) * 64 + ni * 16 + laneM] = acc[mi][ni][r];
        __syncthreads();   // transpose writes visible before reads
#pragma unroll
        for (int kk = 0; kk < 4; ++kk) {
            int rl = kk * 4 + laneQ;           // local row 0..15
            float4 v = *reinterpret_cast<const float4*>(&eps[rl * 64 + ec]);
            float4 o = {v.x + bv.x, v.y + bv.y, v.z + bv.z, v.w + bv.w};
            size_t grow = (size_t)(bm * TILE + wm * 64 + mi * 16 + rl);
            *reinterpret_cast<float4*>(&C[grow * N + bn * TILE + wn * 64 + ec]) = o;
        }
    }
}

extern "C" void kernel_launch(void* const* d_in, const int* in_sizes, int n_in,
                              void* d_out, int out_size, void* d_ws, size_t ws_size,
                              hipStream_t stream) {
    const float* x    = (const float*)d_in[0];   // [M, K]
    const float* w    = (const float*)d_in[1];   // [N, K]
    const float* bias = (const float*)d_in[2];   // [N]
    float* out = (float*)d_out;

    const int K = 2048;                 // IN
    const int N = in_sizes[2];          // OUT = 2048
    const int M = in_sizes[0] / K;      // 8192

    unsigned short* wb = (unsigned short*)d_ws;  // [N,K] bf16 +-1: 8 MB

    const int nw4 = (N * K) / 4;
    bin_w_kernel<<<(nw4 + 255) / 256, 256, 0, stream>>>(w, wb, nw4);

    dim3 grid(N / TILE, M / TILE);      // (16, 64)
    gemm_fused_kernel<<<grid, 256, 0, stream>>>(x, wb, bias, out, M, N, K);
}

// Round 4
// 200.757 us; speedup vs baseline: 1.1569x; 1.1137x over previous
//
#include <hip/hip_runtime.h>
#include <stdint.h>

// ---------------------------------------------------------------------------
// BinaryLinear: out[M,N] = x[M,K] @ sign(W[N,K])^T + bias[N]
// M=8192, K=2048, N=2048, fp32 in/out.
// Round 4: back to separate prep kernels (cvt_x: fp32->bf16, bin_w: sign->bf16
// +-1). GEMM restructured: BK=64 (half the barrier drains), 32x32x16 MFMA
// (2x2 per wave, higher per-instr efficiency), XOR-swizzled LDS layout to
// kill the 8-way bank conflicts BK=64's 128B row stride would cause, while
// keeping global_load_lds width=16 staging (swizzle applied on the global
// source address; LDS dest stays contiguous in tid as the HW requires).
// Epilogue: barrier-fenced LDS transpose -> float4 stores (R3-verified shape).
// ---------------------------------------------------------------------------

typedef __bf16 bf16x8 __attribute__((ext_vector_type(8)));
typedef float f32x16 __attribute__((ext_vector_type(16)));

typedef const __attribute__((address_space(1))) void* gas_ptr;
typedef __attribute__((address_space(3))) void* lds_ptr;

__device__ __forceinline__ unsigned short f2bf_rne(float f) {
    unsigned int u = __builtin_bit_cast(unsigned int, f);
    u += 0x7fffu + ((u >> 16) & 1u);   // round-to-nearest-even
    return (unsigned short)(u >> 16);
}

// x fp32 -> bf16 bits, 8 elems/thread (two float4 loads, one uint4 store)
__global__ __launch_bounds__(256) void cvt_x_kernel(const float* __restrict__ in,
                                                    unsigned short* __restrict__ out,
                                                    int n8) {
    int i = blockIdx.x * 256 + threadIdx.x;
    if (i >= n8) return;
    const float4* p = reinterpret_cast<const float4*>(in + (size_t)i * 8);
    float4 f0 = p[0], f1 = p[1];
    union { unsigned short s[8]; uint4 v; } o;
    o.s[0] = f2bf_rne(f0.x); o.s[1] = f2bf_rne(f0.y);
    o.s[2] = f2bf_rne(f0.z); o.s[3] = f2bf_rne(f0.w);
    o.s[4] = f2bf_rne(f1.x); o.s[5] = f2bf_rne(f1.y);
    o.s[6] = f2bf_rne(f1.z); o.s[7] = f2bf_rne(f1.w);
    *reinterpret_cast<uint4*>(out + (size_t)i * 8) = o.v;
}

// W fp32 -> sign(W) as bf16 bits (+1.0/-1.0). w>=0 -> +1 per reference.
__global__ __launch_bounds__(256) void bin_w_kernel(const float* __restrict__ in,
                                                    unsigned short* __restrict__ out,
                                                    int n4) {
    int i = blockIdx.x * 256 + threadIdx.x;
    if (i >= n4) return;
    float4 f = reinterpret_cast<const float4*>(in)[i];
    union { unsigned short s[4]; uint2 v; } o;
    o.s[0] = (f.x >= 0.f) ? 0x3F80u : 0xBF80u;
    o.s[1] = (f.y >= 0.f) ? 0x3F80u : 0xBF80u;
    o.s[2] = (f.z >= 0.f) ? 0x3F80u : 0xBF80u;
    o.s[3] = (f.w >= 0.f) ? 0x3F80u : 0xBF80u;
    reinterpret_cast<uint2*>(out)[i] = o.v;
}

// ---------------------------------------------------------------------------
// GEMM: C[M,N] = A[M,K](bf16) * B[N,K]^T(bf16 +-1) + bias[N], fp32 out.
// 128x128 tile, BK=64, 4 waves (2x2), each wave 64x64 via 2x2 of
// mfma_f32_32x32x16_bf16 (acc 16 fp32/lane per tile).
//
// LDS layout (per operand, 128 rows x 64 bf16): chunk = 8 bf16 = 16B.
// Physical chunk index of (row, kchunk c) = row*8 + (c ^ (row&7)).
// -> staging thread t round j stages chunk g=j*256+t from global column
//    ((g&7) ^ (row&7))*8, LDS dest = g*16B (contiguous in tid: gld_lds-legal).
// -> reads by lanes 0..31 (rows r..r+31, same c) spread over all 8 bank
//    groups instead of hammering one (128B row stride == 32 banks).
//
// Operand layout 32x32x16_bf16: A[row=lane&31][k=(lane>>5)*8 + 0..7],
// B same with col=lane&31.  C/D: col=lane&31, row=(reg&3)+8*(reg>>2)+
// 4*(lane>>5)  [HW-verified m74/m101].
// ---------------------------------------------------------------------------
#define TILE 128
#define BK   64

__global__ __launch_bounds__(256) void gemm_bin_kernel(
    const unsigned short* __restrict__ A,   // bf16 bits [M][K]
    const unsigned short* __restrict__ B,   // bf16 bits [N][K]
    const float* __restrict__ bias,         // [N]
    float* __restrict__ C,                  // [M][N]
    int M, int N, int K)
{
    __shared__ __align__(16) unsigned char smem[32768];
    unsigned short* Als = (unsigned short*)smem;            // 128x64 swizzled
    unsigned short* Bls = (unsigned short*)(smem + 16384);  // 128x64 swizzled

    const int tid  = threadIdx.x;
    const int lane = tid & 63;
    const int wave = tid >> 6;
    const int wm   = wave & 1;
    const int wn   = wave >> 1;
    const int bm   = blockIdx.y;   // M/128 = 64
    const int bn   = blockIdx.x;   // N/128 = 16

    const unsigned short* Agb = A + (size_t)(bm * TILE) * K;
    const unsigned short* Bgb = B + (size_t)(bn * TILE) * K;

    f32x16 acc[2][2];
#pragma unroll
    for (int a = 0; a < 2; ++a)
#pragma unroll
        for (int b = 0; b < 2; ++b)
#pragma unroll
            for (int r = 0; r < 16; ++r)
                acc[a][b][r] = 0.f;

    const int lr  = lane & 31;   // row (A) / col (B) within 32-tile
    const int lk  = lane >> 5;   // k-half: k = lk*8 + 0..7
    const int swz = lane & 7;    // frag row & 7 (tile row offsets are x32)

    // Precompute staging geometry: round j, thread t -> chunk g = j*256+t.
    int st_row[4], st_col[4];
#pragma unroll
    for (int j = 0; j < 4; ++j) {
        int g = j * 256 + tid;
        st_row[j] = g >> 3;                       // 0..127
        st_col[j] = ((g & 7) ^ (st_row[j] & 7)) * 8;  // swizzled global col
    }

    for (int k0 = 0; k0 < K; k0 += BK) {
        __syncthreads();   // previous iteration's frag reads complete

#pragma unroll
        for (int j = 0; j < 4; ++j) {
            int g = j * 256 + tid;
            __builtin_amdgcn_global_load_lds(
                (gas_ptr)(Agb + (size_t)st_row[j] * K + k0 + st_col[j]),
                (lds_ptr)&Als[g * 8], 16, 0, 0);
        }
#pragma unroll
        for (int j = 0; j < 4; ++j) {
            int g = j * 256 + tid;
            __builtin_amdgcn_global_load_lds(
                (gas_ptr)(Bgb + (size_t)st_row[j] * K + k0 + st_col[j]),
                (lds_ptr)&Bls[g * 8], 16, 0, 0);
        }

        __syncthreads();   // staging complete (vmcnt drained)

#pragma unroll
        for (int ks = 0; ks < 4; ++ks) {
            const int c = ks * 2 + lk;           // k-chunk index 0..7
            bf16x8 af[2], bfv[2];
#pragma unroll
            for (int mi = 0; mi < 2; ++mi) {
                int row = wm * 64 + mi * 32 + lr;
                af[mi] = *reinterpret_cast<const bf16x8*>(
                    &Als[(row * 8 + (c ^ swz)) * 8]);
            }
#pragma unroll
            for (int ni = 0; ni < 2; ++ni) {
                int row = wn * 64 + ni * 32 + lr;
                bfv[ni] = *reinterpret_cast<const bf16x8*>(
                    &Bls[(row * 8 + (c ^ swz)) * 8]);
            }
#pragma unroll
            for (int mi = 0; mi < 2; ++mi)
#pragma unroll
                for (int ni = 0; ni < 2; ++ni)
                    acc[mi][ni] = __builtin_amdgcn_mfma_f32_32x32x16_bf16(
                        af[mi], bfv[ni], acc[mi][ni], 0, 0, 0);
        }
    }

    // Epilogue: per-wave private 32x64 fp32 slab (8 KB; 4 waves = 32 KB,
    // reusing the staging LDS). Transpose from MFMA C/D layout to
    // row-contiguous, then float4 stores (4 rows x 256B per instruction).
    // Barrier-fenced (R2 lesson); all waves execute uniformly.
    float* eps = (float*)smem + wave * 2048;
    const int c4 = (lane & 15) * 4;   // read-phase col (floats), 0..60
    const int pr = lane >> 4;         // read-phase row-in-pass, 0..3
    float4 bv = *(const float4*)&bias[bn * TILE + wn * 64 + c4];

#pragma unroll
    for (int mi = 0; mi < 2; ++mi) {
        __syncthreads();   // slab free (prior frag/epilogue reads done)
#pragma unroll
        for (int ni = 0; ni < 2; ++ni)
#pragma unroll
            for (int r = 0; r < 16; ++r) {
                int rl = (r & 3) + 8 * (r >> 2) + 4 * lk;   // 0..31
                eps[rl * 64 + ni * 32 + lr] = acc[mi][ni][r];
            }
        __syncthreads();   // transpose writes visible before reads
#pragma unroll
        for (int p = 0; p < 8; ++p) {
            int rl = p * 4 + pr;
            float4 v = *reinterpret_cast<const float4*>(&eps[rl * 64 + c4]);
            float4 o = {v.x + bv.x, v.y + bv.y, v.z + bv.z, v.w + bv.w};
            size_t grow = (size_t)(bm * TILE + wm * 64 + mi * 32 + rl);
            *reinterpret_cast<float4*>(&C[grow * N + bn * TILE + wn * 64 + c4]) = o;
        }
    }
}

extern "C" void kernel_launch(void* const* d_in, const int* in_sizes, int n_in,
                              void* d_out, int out_size, void* d_ws, size_t ws_size,
                              hipStream_t stream) {
    const float* x    = (const float*)d_in[0];   // [M, K]
    const float* w    = (const float*)d_in[1];   // [N, K]
    const float* bias = (const float*)d_in[2];   // [N]
    float* out = (float*)d_out;

    const int K = 2048;                 // IN
    const int N = in_sizes[2];          // OUT = 2048
    const int M = in_sizes[0] / K;      // 8192

    unsigned short* xb = (unsigned short*)d_ws;   // [M,K] bf16: 32 MB
    unsigned short* wb = xb + (size_t)M * K;      // [N,K] bf16 +-1: 8 MB

    const int nx8 = (M * K) / 8;
    const int nw4 = (N * K) / 4;
    cvt_x_kernel<<<(nx8 + 255) / 256, 256, 0, stream>>>(x, xb, nx8);
    bin_w_kernel<<<(nw4 + 255) / 256, 256, 0, stream>>>(w, wb, nw4);

    dim3 grid(N / TILE, M / TILE);      // (16, 64)
    gemm_bin_kernel<<<grid, 256, 0, stream>>>(xb, wb, bias, out, M, N, K);
}